// Round 11
// baseline (339.053 us; speedup 1.0000x reference)
//
#include <hip/hip_runtime.h>

typedef short short8 __attribute__((ext_vector_type(8)));
typedef float floatx4 __attribute__((ext_vector_type(4)));

__device__ __forceinline__ unsigned short f2bf(float f) {
  unsigned int u = __float_as_uint(f);
  u += 0x7FFFu + ((u >> 16) & 1u);   // RNE
  return (unsigned short)(u >> 16);
}

#if __has_builtin(__builtin_amdgcn_cvt_pk_bf16_f32)
typedef __bf16 bf16x2_t __attribute__((ext_vector_type(2)));
__device__ __forceinline__ unsigned int pk2bf(float lo, float hi) {
  bf16x2_t v = __builtin_amdgcn_cvt_pk_bf16_f32(lo, hi);
  return __builtin_bit_cast(unsigned int, v);
}
#else
__device__ __forceinline__ unsigned int pk2bf(float lo, float hi) {
  return (unsigned)f2bf(lo) | ((unsigned)f2bf(hi) << 16);
}
#endif

__device__ __forceinline__ float silu(float h) {
  return h * __builtin_amdgcn_rcpf(1.f + __expf(-h));
}

// ---------------------------------------------------------------------------
// Mega-setup (one dispatch, independent jobs by block range): nodeA tables |
// zero d_out | col histogram | W2x repack. (Layout notes in R10.)
// ---------------------------------------------------------------------------
__global__ __launch_bounds__(256) void k_mega(
    float* __restrict__ out, int out_n,
    const int* __restrict__ colp, int E, int* __restrict__ hist,
    const float* __restrict__ x, int N,
    const float* __restrict__ W1x, const float* __restrict__ W1p,
    const float* __restrict__ W2x,
    const float* __restrict__ b1x, const float* __restrict__ b1p,
    unsigned short* __restrict__ wbuf,
    unsigned int* __restrict__ Ar, unsigned int* __restrict__ Ac,
    int b1, int b2, int b3)
{
  __shared__ __align__(16) unsigned short xt[64][72];
  const int blk = blockIdx.x, t = threadIdx.x;

  if (blk < b1) {
    // ---------------- job nodeA ----------------
    const int n0 = blk * 64;
    const int wv = t >> 6, lane = t & 63, quad = lane >> 4, lc = lane & 15;

    {  // stage x tile (bf16)
      int nd = t >> 2, p = t & 3;
      int n = n0 + nd;
      uint4 o0, o1;
      if (n < N) {
        const float4* xp = (const float4*)(x + (size_t)n*64 + p*16);
        float4 a = xp[0], b = xp[1], c = xp[2], d = xp[3];
        o0 = make_uint4(pk2bf(a.x,a.y), pk2bf(a.z,a.w), pk2bf(b.x,b.y), pk2bf(b.z,b.w));
        o1 = make_uint4(pk2bf(c.x,c.y), pk2bf(c.z,c.w), pk2bf(d.x,d.y), pk2bf(d.z,d.w));
      } else {
        o0 = o1 = make_uint4(0u,0u,0u,0u);
      }
      *(uint4*)&xt[nd][p*16]     = o0;
      *(uint4*)&xt[nd][p*16 + 8] = o1;
    }

    // inline W1 fragment conversion from f32 (L2-hot)
    short8 fxr[2][2], fxc[2][2], fpr[2][2], fpc[2][2];
    float bxv[2][4], bpv[2][4];
    #pragma unroll
    for (int ti = 0; ti < 2; ++ti) {
      const int nt = wv + 4*ti;
      const int n  = nt*16 + lc;
      #pragma unroll
      for (int k2 = 0; k2 < 2; ++k2) {
        #pragma unroll
        for (int j = 0; j < 8; ++j) {
          const int kr = k2*32 + quad*8 + j;          // 0..63
          fxr[ti][k2][j] = (short)f2bf(W1x[kr*128 + n]);
          fxc[ti][k2][j] = (short)f2bf(W1x[(64 + kr)*128 + n]);
          fpr[ti][k2][j] = (short)f2bf(W1p[kr*128 + n]);
          fpc[ti][k2][j] = (short)f2bf(W1p[(64 + kr)*128 + n]);
        }
      }
      #pragma unroll
      for (int r = 0; r < 4; ++r) {
        bxv[ti][r] = b1x[nt*16 + quad*4 + r];
        bpv[ti][r] = b1p[nt*16 + quad*4 + r];
      }
    }
    __syncthreads();

    #pragma unroll 1
    for (int mw = 0; mw < 4; ++mw) {
      short8 bb0 = *(const short8*)&xt[mw*16 + lc][quad*8];       // k 0..31
      short8 bb1 = *(const short8*)&xt[mw*16 + lc][32 + quad*8];  // k 32..63
      const int nd = n0 + mw*16 + lc;
      #pragma unroll
      for (int ti = 0; ti < 2; ++ti) {
        floatx4 xr = {0,0,0,0}, xc = {0,0,0,0}, pr = {0,0,0,0}, pc = {0,0,0,0};
        xr = __builtin_amdgcn_mfma_f32_16x16x32_bf16(fxr[ti][0], bb0, xr, 0,0,0);
        xr = __builtin_amdgcn_mfma_f32_16x16x32_bf16(fxr[ti][1], bb1, xr, 0,0,0);
        xc = __builtin_amdgcn_mfma_f32_16x16x32_bf16(fxc[ti][0], bb0, xc, 0,0,0);
        xc = __builtin_amdgcn_mfma_f32_16x16x32_bf16(fxc[ti][1], bb1, xc, 0,0,0);
        pr = __builtin_amdgcn_mfma_f32_16x16x32_bf16(fpr[ti][0], bb0, pr, 0,0,0);
        pr = __builtin_amdgcn_mfma_f32_16x16x32_bf16(fpr[ti][1], bb1, pr, 0,0,0);
        pc = __builtin_amdgcn_mfma_f32_16x16x32_bf16(fpc[ti][0], bb0, pc, 0,0,0);
        pc = __builtin_amdgcn_mfma_f32_16x16x32_bf16(fpc[ti][1], bb1, pc, 0,0,0);
        if (nd < N) {
          const int hbase = (wv + 4*ti)*16 + quad*4;
          uint4 ur = make_uint4(pk2bf(xr[0]+bxv[ti][0], pr[0]+bpv[ti][0]),
                                pk2bf(xr[1]+bxv[ti][1], pr[1]+bpv[ti][1]),
                                pk2bf(xr[2]+bxv[ti][2], pr[2]+bpv[ti][2]),
                                pk2bf(xr[3]+bxv[ti][3], pr[3]+bpv[ti][3]));
          uint4 uc = make_uint4(pk2bf(xc[0], pc[0]), pk2bf(xc[1], pc[1]),
                                pk2bf(xc[2], pc[2]), pk2bf(xc[3], pc[3]));
          *(uint4*)(Ar + (size_t)nd*128 + hbase) = ur;
          *(uint4*)(Ac + (size_t)nd*128 + hbase) = uc;
        }
      }
    }
  } else if (blk < b2) {
    // ---------------- job zero d_out ----------------
    int i = ((blk - b1) * 256 + t) * 16;
    #pragma unroll
    for (int q = 0; q < 4; ++q) {
      int j = i + q*4;
      if (j + 4 <= out_n) *(float4*)(out + j) = make_float4(0.f,0.f,0.f,0.f);
      else for (int k = j; k < out_n; ++k) out[k] = 0.f;
    }
  } else if (blk < b3) {
    // ---------------- job histogram ----------------
    int i4 = (blk - b2) * 256 + t;
    if (i4 < (E >> 2)) {
      int4 c = *(const int4*)(colp + i4*4);
      atomicAdd(&hist[c.x], 1); atomicAdd(&hist[c.y], 1);
      atomicAdd(&hist[c.z], 1); atomicAdd(&hist[c.w], 1);
    }
    if (blk == b2 && t == 0)
      for (int k = E & ~3; k < E; ++k) atomicAdd(&hist[colp[k]], 1);
  } else {
    // ---------------- job repack W2x ----------------
    int i = (blk - b3) * 256 + t;
    if (i < 8192) {
      int jj = i & 7, lane = (i >> 3) & 63, ks = (i >> 9) & 3, nt = (i >> 11) & 3;
      int k = ks*32 + (lane >> 4)*8 + jj;
      wbuf[i] = f2bf(W2x[k*64 + nt*16 + (lane & 15)]);
    }
  }
}

// ---------------------------------------------------------------------------
// Counting-sort scan (49 blocks)
// ---------------------------------------------------------------------------
__global__ __launch_bounds__(256) void k_scan_a(
    int* __restrict__ hist, int N, int* __restrict__ bsum) {
  __shared__ int wtot[4], wexc[4];
  int t = threadIdx.x, lane = t & 63, w = t >> 6;
  int base = blockIdx.x * 1024 + t * 4;
  int v0 = (base + 0 < N) ? hist[base + 0] : 0;
  int v1 = (base + 1 < N) ? hist[base + 1] : 0;
  int v2 = (base + 2 < N) ? hist[base + 2] : 0;
  int v3 = (base + 3 < N) ? hist[base + 3] : 0;
  int T = v0 + v1 + v2 + v3;
  int inc = T;
  #pragma unroll
  for (int s = 1; s < 64; s <<= 1) {
    int u = __shfl_up(inc, s, 64);
    if (lane >= s) inc += u;
  }
  if (lane == 63) wtot[w] = inc;
  __syncthreads();
  if (t == 0) {
    int a = 0;
    #pragma unroll
    for (int i = 0; i < 4; ++i) { wexc[i] = a; a += wtot[i]; }
    bsum[blockIdx.x] = a;
  }
  __syncthreads();
  int tex = wexc[w] + (inc - T);
  if (base + 0 < N) hist[base + 0] = tex;
  if (base + 1 < N) hist[base + 1] = tex + v0;
  if (base + 2 < N) hist[base + 2] = tex + v0 + v1;
  if (base + 3 < N) hist[base + 3] = tex + v0 + v1 + v2;
}

// ---------------------------------------------------------------------------
// Scatter (4 edges/thread) with inline top-scan of bsum (NB<=64)
// ---------------------------------------------------------------------------
__global__ __launch_bounds__(256) void k_scatter(
    const int* __restrict__ row, const int* __restrict__ col, int E,
    int* __restrict__ excl, const int* __restrict__ bsum, int NB,
    int2* __restrict__ sedge) {
  __shared__ int boff_sh[64];
  int t = threadIdx.x;
  if (t < 64) {
    int v = (t < NB) ? bsum[t] : 0;
    int inc = v;
    #pragma unroll
    for (int s = 1; s < 64; s <<= 1) {
      int u = __shfl_up(inc, s, 64);
      if (t >= s) inc += u;
    }
    boff_sh[t] = inc - v;
  }
  __syncthreads();
  int i4 = blockIdx.x * 256 + t;
  if (i4 < (E >> 2)) {
    int4 c = *(const int4*)(col + i4*4);
    int4 r = *(const int4*)(row + i4*4);
    int p;
    p = atomicAdd(&excl[c.x], 1) + boff_sh[c.x >> 10]; sedge[p] = make_int2(r.x, c.x);
    p = atomicAdd(&excl[c.y], 1) + boff_sh[c.y >> 10]; sedge[p] = make_int2(r.y, c.y);
    p = atomicAdd(&excl[c.z], 1) + boff_sh[c.z >> 10]; sedge[p] = make_int2(r.z, c.z);
    p = atomicAdd(&excl[c.w], 1) + boff_sh[c.w >> 10]; sedge[p] = make_int2(r.w, c.w);
  }
  if (blockIdx.x == 0 && t == 0) {
    for (int k = E & ~3; k < E; ++k) {
      int c = col[k];
      int p = atomicAdd(&excl[c], 1) + boff_sh[c >> 10];
      sedge[p] = make_int2(row[k], c);
    }
  }
}

// ---------------------------------------------------------------------------
// Main kernel: 512 threads = TWO independent 64-edge tiles per block
// (waves 0-3 <-> tile 0, waves 4-7 <-> tile 1, disjoint LDS halves).
// Per-wave structure identical to R10's proven 137us kernel; doubling
// waves/block raises resident waves for gather-latency hiding.
// ---------------------------------------------------------------------------
__global__ __launch_bounds__(512) void mp_main(
    const float* __restrict__ pos,
    const int2* __restrict__ sedge, int E,
    const unsigned int* __restrict__ Ar, const unsigned int* __restrict__ Ac,
    const float* __restrict__ W1x, const float* __restrict__ W1p,
    const float* __restrict__ b2x, const float* __restrict__ W2p,
    const float* __restrict__ b2p,
    const unsigned short* __restrict__ wbuf,
    float* __restrict__ out_x, float* __restrict__ out_pos)
{
  __shared__ __align__(16) unsigned short H_lds[2][64][136];  // 34816 B
  __shared__ __align__(16) uint4 edata[2][64];                // {row,col,dsq,0}
  __shared__ float rel_lds[2][64][3];
  __shared__ int   col_sh[2][64];
  __shared__ float wsum[2][4][64];

  const int t    = threadIdx.x;
  const int wv   = t >> 6;        // 0..7
  const int half = wv >> 2;       // tile index 0/1
  const int lw   = wv & 3;        // wave role within tile
  const int lane = t & 63;
  const int quad = lane >> 4;
  const int lc   = lane & 15;
  const int e0   = blockIdx.x * 128;

  // ---- phase 1: per-edge scalars for both tiles (threads 0..127) ----
  if (t < 128) {
    const int tl = t >> 6, j = t & 63;
    int e = e0 + tl*64 + j;
    int r = 0, c = 0, cs = -1;
    float rp0 = 0.f, rp1 = 0.f, rp2 = 0.f, dsq = 0.f;
    if (e < E) {
      int2 rc = sedge[e]; r = rc.x; c = rc.y;
      cs = c;
      float pr0 = pos[r*3+0], pr1 = pos[r*3+1], pr2 = pos[r*3+2];
      float pc0 = pos[c*3+0], pc1 = pos[c*3+1], pc2 = pos[c*3+2];
      rp0 = pr0 - pc0; rp1 = pr1 - pc1; rp2 = pr2 - pc2;
      dsq = rp0*rp0 + rp1*rp1 + rp2*rp2;
    }
    rel_lds[tl][j][0] = rp0; rel_lds[tl][j][1] = rp1; rel_lds[tl][j][2] = rp2;
    col_sh[tl][j] = cs;
    edata[tl][j] = make_uint4((unsigned)r, (unsigned)c, __float_as_uint(dsq), 0u);
  }

  const short8* __restrict__ w2x_f = (const short8*)wbuf;
  short8 a2w[4];
  #pragma unroll
  for (int ks = 0; ks < 4; ++ks) a2w[ks] = w2x_f[(lw*4 + ks)*64 + lane];

  float w1xd[2][4], w1pd[2][4], wp2[2][4], b2xr[4];
  #pragma unroll
  for (int ti = 0; ti < 2; ++ti)
    #pragma unroll
    for (int r = 0; r < 4; ++r) {
      int h = (lw + 4*ti)*16 + quad*4 + r;
      w1xd[ti][r] = W1x[16384 + h];     // dist^2 row (row 128 of [129][128])
      w1pd[ti][r] = W1p[16384 + h];
      wp2[ti][r]  = W2p[h];
    }
  #pragma unroll
  for (int r = 0; r < 4; ++r) b2xr[r] = b2x[lw*16 + quad*4 + r];
  const float b2ps = b2p[0];
  __syncthreads();

  // ---- layer 1: table gather + silu -> H_lds; phi_p dot -> wsum ----
  #pragma unroll 2
  for (int et = 0; et < 4; ++et) {
    uint4 ed = edata[half][et*16 + lc];
    const float dsqv = __uint_as_float(ed.z);
    float ps = 0.f;
    #pragma unroll
    for (int ti = 0; ti < 2; ++ti) {
      const int ht = lw + 4*ti;
      const int hb = ht*32 + quad*8;
      uint4 va = *(const uint4*)((const unsigned short*)Ar + (size_t)ed.x*256 + hb);
      uint4 vc = *(const uint4*)((const unsigned short*)Ac + (size_t)ed.y*256 + hb);
      float sx[4];
      #pragma unroll
      for (int j = 0; j < 4; ++j) {
        unsigned a = (&va.x)[j], bb = (&vc.x)[j];
        float hx = __uint_as_float(a << 16) + __uint_as_float(bb << 16)
                 + dsqv * w1xd[ti][j];
        float hp = __uint_as_float(a & 0xffff0000u) + __uint_as_float(bb & 0xffff0000u)
                 + dsqv * w1pd[ti][j];
        sx[j] = silu(hx);
        ps += silu(hp) * wp2[ti][j];
      }
      *(uint2*)&H_lds[half][et*16 + lc][ht*16 + quad*4] =
          make_uint2(pk2bf(sx[0], sx[1]), pk2bf(sx[2], sx[3]));
    }
    ps += __shfl_xor(ps, 16, 64);
    ps += __shfl_xor(ps, 32, 64);
    if (lane < 16) wsum[half][lw][et*16 + lane] = ps;
  }
  __syncthreads();

  // ---- layer 2: MFMA + segmented-reduce scatter ----
  #pragma unroll 2
  for (int et = 0; et < 4; ++et) {
    floatx4 acc = {0,0,0,0};
    #pragma unroll
    for (int ks = 0; ks < 4; ++ks) {
      short8 b = *(const short8*)&H_lds[half][et*16 + lc][ks*32 + quad*8];
      acc = __builtin_amdgcn_mfma_f32_16x16x32_bf16(a2w[ks], b, acc, 0, 0, 0);
    }
    int edge = et*16 + lc;
    int myc = col_sh[half][edge];
    float v0 = acc[0] + b2xr[0], v1 = acc[1] + b2xr[1];
    float v2 = acc[2] + b2xr[2], v3 = acc[3] + b2xr[3];
    #pragma unroll
    for (int s = 1; s < 16; s <<= 1) {
      int   nc = __shfl_down(myc, s, 64);
      float n0 = __shfl_down(v0,  s, 64);
      float n1 = __shfl_down(v1,  s, 64);
      float n2 = __shfl_down(v2,  s, 64);
      float n3 = __shfl_down(v3,  s, 64);
      if ((lc + s < 16) && (nc == myc)) { v0 += n0; v1 += n1; v2 += n2; v3 += n3; }
    }
    bool head = (myc >= 0) && (lc == 0 || col_sh[half][edge-1] != myc);
    if (head) {
      float* dst = out_x + (size_t)myc*64 + lw*16 + quad*4;
      atomicAdd(dst + 0, v0);
      atomicAdd(dst + 1, v1);
      atomicAdd(dst + 2, v2);
      atomicAdd(dst + 3, v3);
    }
  }

  // ---- phi_p epilogue (threads 0..127; wave 0 = tile 0, wave 1 = tile 1) --
  if (t < 128) {
    const int tl = t >> 6, j = t & 63;
    int c = col_sh[tl][j];
    float w = wsum[tl][0][j] + wsum[tl][1][j] + wsum[tl][2][j] + wsum[tl][3][j]
            + b2ps;
    float p0 = w * rel_lds[tl][j][0];
    float p1 = w * rel_lds[tl][j][1];
    float p2 = w * rel_lds[tl][j][2];
    #pragma unroll
    for (int s = 1; s < 64; s <<= 1) {
      int   nc = __shfl_down(c,  s, 64);
      float n0 = __shfl_down(p0, s, 64);
      float n1 = __shfl_down(p1, s, 64);
      float n2 = __shfl_down(p2, s, 64);
      if ((j + s < 64) && (nc == c)) { p0 += n0; p1 += n1; p2 += n2; }
    }
    bool head = (c >= 0) && (j == 0 || col_sh[tl][j-1] != c);
    if (head) {
      atomicAdd(&out_pos[(size_t)c*3 + 0], p0);
      atomicAdd(&out_pos[(size_t)c*3 + 1], p1);
      atomicAdd(&out_pos[(size_t)c*3 + 2], p2);
    }
  }
}

extern "C" void kernel_launch(void* const* d_in, const int* in_sizes, int n_in,
                              void* d_out, int out_size, void* d_ws, size_t ws_size,
                              hipStream_t stream) {
  const float* x   = (const float*)d_in[0];
  const float* pos = (const float*)d_in[1];
  const int*   ei  = (const int*)d_in[2];
  const float* W1x = (const float*)d_in[3];
  const float* b1x = (const float*)d_in[4];
  const float* W2x = (const float*)d_in[5];
  const float* b2x = (const float*)d_in[6];
  const float* W1p = (const float*)d_in[7];
  const float* b1p = (const float*)d_in[8];
  const float* W2p = (const float*)d_in[9];
  const float* b2p = (const float*)d_in[10];

  const int E = in_sizes[2] / 2;        // 800000
  const int N = in_sizes[0] / 64;       // 50000
  const int* rowp = ei;
  const int* colp = ei + E;
  float* out_x   = (float*)d_out;
  float* out_pos = out_x + (size_t)N * 64;
  const int NB = (N + 1023) / 1024;     // 49

  // ws layout: [Ar][Ac][wbuf(W2 frags)][hist][bsum][sedge]
  char* ws = (char*)d_ws;
  const size_t tab_one = (size_t)N * 512;
  unsigned int*   Ar   = (unsigned int*)ws;
  unsigned int*   Ac   = (unsigned int*)(ws + tab_one);
  unsigned short* wbuf = (unsigned short*)(ws + 2*tab_one);
  int*  hist  = (int*)(ws + 2*tab_one + 16384);
  int*  bsum  = (int*)(ws + 2*tab_one + 16384 + 200192);
  int2* sedge = (int2*)(ws + 2*tab_one + 16384 + 200192 + 512);

  hipMemsetAsync(hist, 0, (size_t)N * sizeof(int), stream);

  // mega-setup: nodeA | zero d_out | histogram | repack W2x
  const int nb_node = (N + 63) / 64;                 // 782
  const int nb_zero = (out_size + 4095) / 4096;      // 818
  const int nb_hist = ((E >> 2) + 255) / 256;        // 782
  const int nb_rep  = 32;
  const int b1 = nb_node, b2 = b1 + nb_zero, b3 = b2 + nb_hist;
  k_mega<<<b3 + nb_rep, 256, 0, stream>>>(
      (float*)d_out, out_size, colp, E, hist, x, N,
      W1x, W1p, W2x, b1x, b1p, wbuf, Ar, Ac, b1, b2, b3);

  k_scan_a<<<NB, 256, 0, stream>>>(hist, N, bsum);
  k_scatter<<<((E >> 2) + 255) / 256, 256, 0, stream>>>(
      rowp, colp, E, hist, bsum, NB, sedge);

  mp_main<<<(E + 127) / 128, 512, 0, stream>>>(
      pos, sedge, E, Ar, Ac, W1x, W1p, b2x, W2p, b2p, wbuf, out_x, out_pos);
}

// Round 12
// 330.444 us; speedup vs baseline: 1.0261x; 1.0261x over previous
//
#include <hip/hip_runtime.h>

typedef short short8 __attribute__((ext_vector_type(8)));
typedef float floatx4 __attribute__((ext_vector_type(4)));

__device__ __forceinline__ unsigned short f2bf(float f) {
  unsigned int u = __float_as_uint(f);
  u += 0x7FFFu + ((u >> 16) & 1u);   // RNE
  return (unsigned short)(u >> 16);
}

#if __has_builtin(__builtin_amdgcn_cvt_pk_bf16_f32)
typedef __bf16 bf16x2_t __attribute__((ext_vector_type(2)));
__device__ __forceinline__ unsigned int pk2bf(float lo, float hi) {
  bf16x2_t v = __builtin_amdgcn_cvt_pk_bf16_f32(lo, hi);
  return __builtin_bit_cast(unsigned int, v);
}
#else
__device__ __forceinline__ unsigned int pk2bf(float lo, float hi) {
  return (unsigned)f2bf(lo) | ((unsigned)f2bf(hi) << 16);
}
#endif

__device__ __forceinline__ float silu(float h) {
  return h * __builtin_amdgcn_rcpf(1.f + __expf(-h));
}

// ---------------------------------------------------------------------------
// Mega-setup (one dispatch, independent jobs by block range): nodeA tables |
// zero d_out | col histogram | W2x repack. (Layout notes in R10.)
// ---------------------------------------------------------------------------
__global__ __launch_bounds__(256) void k_mega(
    float* __restrict__ out, int out_n,
    const int* __restrict__ colp, int E, int* __restrict__ hist,
    const float* __restrict__ x, int N,
    const float* __restrict__ W1x, const float* __restrict__ W1p,
    const float* __restrict__ W2x,
    const float* __restrict__ b1x, const float* __restrict__ b1p,
    unsigned short* __restrict__ wbuf,
    unsigned int* __restrict__ Ar, unsigned int* __restrict__ Ac,
    int b1, int b2, int b3)
{
  __shared__ __align__(16) unsigned short xt[64][72];
  const int blk = blockIdx.x, t = threadIdx.x;

  if (blk < b1) {
    // ---------------- job nodeA ----------------
    const int n0 = blk * 64;
    const int wv = t >> 6, lane = t & 63, quad = lane >> 4, lc = lane & 15;

    {  // stage x tile (bf16)
      int nd = t >> 2, p = t & 3;
      int n = n0 + nd;
      uint4 o0, o1;
      if (n < N) {
        const float4* xp = (const float4*)(x + (size_t)n*64 + p*16);
        float4 a = xp[0], b = xp[1], c = xp[2], d = xp[3];
        o0 = make_uint4(pk2bf(a.x,a.y), pk2bf(a.z,a.w), pk2bf(b.x,b.y), pk2bf(b.z,b.w));
        o1 = make_uint4(pk2bf(c.x,c.y), pk2bf(c.z,c.w), pk2bf(d.x,d.y), pk2bf(d.z,d.w));
      } else {
        o0 = o1 = make_uint4(0u,0u,0u,0u);
      }
      *(uint4*)&xt[nd][p*16]     = o0;
      *(uint4*)&xt[nd][p*16 + 8] = o1;
    }

    // inline W1 fragment conversion from f32 (L2-hot)
    short8 fxr[2][2], fxc[2][2], fpr[2][2], fpc[2][2];
    float bxv[2][4], bpv[2][4];
    #pragma unroll
    for (int ti = 0; ti < 2; ++ti) {
      const int nt = wv + 4*ti;
      const int n  = nt*16 + lc;
      #pragma unroll
      for (int k2 = 0; k2 < 2; ++k2) {
        #pragma unroll
        for (int j = 0; j < 8; ++j) {
          const int kr = k2*32 + quad*8 + j;          // 0..63
          fxr[ti][k2][j] = (short)f2bf(W1x[kr*128 + n]);
          fxc[ti][k2][j] = (short)f2bf(W1x[(64 + kr)*128 + n]);
          fpr[ti][k2][j] = (short)f2bf(W1p[kr*128 + n]);
          fpc[ti][k2][j] = (short)f2bf(W1p[(64 + kr)*128 + n]);
        }
      }
      #pragma unroll
      for (int r = 0; r < 4; ++r) {
        bxv[ti][r] = b1x[nt*16 + quad*4 + r];
        bpv[ti][r] = b1p[nt*16 + quad*4 + r];
      }
    }
    __syncthreads();

    #pragma unroll 1
    for (int mw = 0; mw < 4; ++mw) {
      short8 bb0 = *(const short8*)&xt[mw*16 + lc][quad*8];       // k 0..31
      short8 bb1 = *(const short8*)&xt[mw*16 + lc][32 + quad*8];  // k 32..63
      const int nd = n0 + mw*16 + lc;
      #pragma unroll
      for (int ti = 0; ti < 2; ++ti) {
        floatx4 xr = {0,0,0,0}, xc = {0,0,0,0}, pr = {0,0,0,0}, pc = {0,0,0,0};
        xr = __builtin_amdgcn_mfma_f32_16x16x32_bf16(fxr[ti][0], bb0, xr, 0,0,0);
        xr = __builtin_amdgcn_mfma_f32_16x16x32_bf16(fxr[ti][1], bb1, xr, 0,0,0);
        xc = __builtin_amdgcn_mfma_f32_16x16x32_bf16(fxc[ti][0], bb0, xc, 0,0,0);
        xc = __builtin_amdgcn_mfma_f32_16x16x32_bf16(fxc[ti][1], bb1, xc, 0,0,0);
        pr = __builtin_amdgcn_mfma_f32_16x16x32_bf16(fpr[ti][0], bb0, pr, 0,0,0);
        pr = __builtin_amdgcn_mfma_f32_16x16x32_bf16(fpr[ti][1], bb1, pr, 0,0,0);
        pc = __builtin_amdgcn_mfma_f32_16x16x32_bf16(fpc[ti][0], bb0, pc, 0,0,0);
        pc = __builtin_amdgcn_mfma_f32_16x16x32_bf16(fpc[ti][1], bb1, pc, 0,0,0);
        if (nd < N) {
          const int hbase = (wv + 4*ti)*16 + quad*4;
          uint4 ur = make_uint4(pk2bf(xr[0]+bxv[ti][0], pr[0]+bpv[ti][0]),
                                pk2bf(xr[1]+bxv[ti][1], pr[1]+bpv[ti][1]),
                                pk2bf(xr[2]+bxv[ti][2], pr[2]+bpv[ti][2]),
                                pk2bf(xr[3]+bxv[ti][3], pr[3]+bpv[ti][3]));
          uint4 uc = make_uint4(pk2bf(xc[0], pc[0]), pk2bf(xc[1], pc[1]),
                                pk2bf(xc[2], pc[2]), pk2bf(xc[3], pc[3]));
          *(uint4*)(Ar + (size_t)nd*128 + hbase) = ur;
          *(uint4*)(Ac + (size_t)nd*128 + hbase) = uc;
        }
      }
    }
  } else if (blk < b2) {
    // ---------------- job zero d_out ----------------
    int i = ((blk - b1) * 256 + t) * 16;
    #pragma unroll
    for (int q = 0; q < 4; ++q) {
      int j = i + q*4;
      if (j + 4 <= out_n) *(float4*)(out + j) = make_float4(0.f,0.f,0.f,0.f);
      else for (int k = j; k < out_n; ++k) out[k] = 0.f;
    }
  } else if (blk < b3) {
    // ---------------- job histogram ----------------
    int i4 = (blk - b2) * 256 + t;
    if (i4 < (E >> 2)) {
      int4 c = *(const int4*)(colp + i4*4);
      atomicAdd(&hist[c.x], 1); atomicAdd(&hist[c.y], 1);
      atomicAdd(&hist[c.z], 1); atomicAdd(&hist[c.w], 1);
    }
    if (blk == b2 && t == 0)
      for (int k = E & ~3; k < E; ++k) atomicAdd(&hist[colp[k]], 1);
  } else {
    // ---------------- job repack W2x ----------------
    int i = (blk - b3) * 256 + t;
    if (i < 8192) {
      int jj = i & 7, lane = (i >> 3) & 63, ks = (i >> 9) & 3, nt = (i >> 11) & 3;
      int k = ks*32 + (lane >> 4)*8 + jj;
      wbuf[i] = f2bf(W2x[k*64 + nt*16 + (lane & 15)]);
    }
  }
}

// ---------------------------------------------------------------------------
// Counting-sort scan (49 blocks)
// ---------------------------------------------------------------------------
__global__ __launch_bounds__(256) void k_scan_a(
    int* __restrict__ hist, int N, int* __restrict__ bsum) {
  __shared__ int wtot[4], wexc[4];
  int t = threadIdx.x, lane = t & 63, w = t >> 6;
  int base = blockIdx.x * 1024 + t * 4;
  int v0 = (base + 0 < N) ? hist[base + 0] : 0;
  int v1 = (base + 1 < N) ? hist[base + 1] : 0;
  int v2 = (base + 2 < N) ? hist[base + 2] : 0;
  int v3 = (base + 3 < N) ? hist[base + 3] : 0;
  int T = v0 + v1 + v2 + v3;
  int inc = T;
  #pragma unroll
  for (int s = 1; s < 64; s <<= 1) {
    int u = __shfl_up(inc, s, 64);
    if (lane >= s) inc += u;
  }
  if (lane == 63) wtot[w] = inc;
  __syncthreads();
  if (t == 0) {
    int a = 0;
    #pragma unroll
    for (int i = 0; i < 4; ++i) { wexc[i] = a; a += wtot[i]; }
    bsum[blockIdx.x] = a;
  }
  __syncthreads();
  int tex = wexc[w] + (inc - T);
  if (base + 0 < N) hist[base + 0] = tex;
  if (base + 1 < N) hist[base + 1] = tex + v0;
  if (base + 2 < N) hist[base + 2] = tex + v0 + v1;
  if (base + 3 < N) hist[base + 3] = tex + v0 + v1 + v2;
}

// ---------------------------------------------------------------------------
// Scatter (4 edges/thread) with inline top-scan of bsum (NB<=64)
// ---------------------------------------------------------------------------
__global__ __launch_bounds__(256) void k_scatter(
    const int* __restrict__ row, const int* __restrict__ col, int E,
    int* __restrict__ excl, const int* __restrict__ bsum, int NB,
    int2* __restrict__ sedge) {
  __shared__ int boff_sh[64];
  int t = threadIdx.x;
  if (t < 64) {
    int v = (t < NB) ? bsum[t] : 0;
    int inc = v;
    #pragma unroll
    for (int s = 1; s < 64; s <<= 1) {
      int u = __shfl_up(inc, s, 64);
      if (t >= s) inc += u;
    }
    boff_sh[t] = inc - v;
  }
  __syncthreads();
  int i4 = blockIdx.x * 256 + t;
  if (i4 < (E >> 2)) {
    int4 c = *(const int4*)(col + i4*4);
    int4 r = *(const int4*)(row + i4*4);
    int p;
    p = atomicAdd(&excl[c.x], 1) + boff_sh[c.x >> 10]; sedge[p] = make_int2(r.x, c.x);
    p = atomicAdd(&excl[c.y], 1) + boff_sh[c.y >> 10]; sedge[p] = make_int2(r.y, c.y);
    p = atomicAdd(&excl[c.z], 1) + boff_sh[c.z >> 10]; sedge[p] = make_int2(r.z, c.z);
    p = atomicAdd(&excl[c.w], 1) + boff_sh[c.w >> 10]; sedge[p] = make_int2(r.w, c.w);
  }
  if (blockIdx.x == 0 && t == 0) {
    for (int k = E & ~3; k < E; ++k) {
      int c = col[k];
      int p = atomicAdd(&excl[c], 1) + boff_sh[c >> 10];
      sedge[p] = make_int2(row[k], c);
    }
  }
}

// ---------------------------------------------------------------------------
// Main kernel (R10 structure, latency-optimized): 64 sorted edges/block,
// 256 threads. Changes vs R10:
//  * barrier #1 removed — every wave self-loads its 64 edges' sedge/pos
//    (coalesced; redundancy absorbed by L1) and broadcasts row/col/dsq via
//    __shfl from the holding lane; table gathers start at cycle ~0.
//  * layer 1 fully unrolled with explicit issue/process split: all 16
//    uint4 table gathers in flight per wave (~2x memory-level parallelism).
// Layer 2 + epilogue unchanged (segmented suffix-sum over sorted cols).
// ---------------------------------------------------------------------------
__global__ __launch_bounds__(256) void mp_main(
    const float* __restrict__ pos,
    const int2* __restrict__ sedge, int E,
    const unsigned int* __restrict__ Ar, const unsigned int* __restrict__ Ac,
    const float* __restrict__ W1x, const float* __restrict__ W1p,
    const float* __restrict__ b2x, const float* __restrict__ W2p,
    const float* __restrict__ b2p,
    const unsigned short* __restrict__ wbuf,
    float* __restrict__ out_x, float* __restrict__ out_pos)
{
  __shared__ __align__(16) unsigned short H_lds[64][136];  // 17408 B
  __shared__ float rel_lds[64][3];
  __shared__ int   col_sh[64];
  __shared__ float wsum[4][64];

  const int t    = threadIdx.x;
  const int e0   = blockIdx.x * 64;
  const int wv   = t >> 6;
  const int lane = t & 63;
  const int quad = lane >> 4;
  const int lc   = lane & 15;

  // ---- every wave: lane i holds edge e0+i (no barrier needed) ----
  int erow = 0, ecol = 0, cs = -1;
  float dsq = 0.f, rp0 = 0.f, rp1 = 0.f, rp2 = 0.f;
  {
    int e = e0 + lane;
    if (e < E) {
      int2 rc = sedge[e];
      erow = rc.x; ecol = rc.y; cs = ecol;
      float pr0 = pos[erow*3+0], pr1 = pos[erow*3+1], pr2 = pos[erow*3+2];
      float pc0 = pos[ecol*3+0], pc1 = pos[ecol*3+1], pc2 = pos[ecol*3+2];
      rp0 = pr0 - pc0; rp1 = pr1 - pc1; rp2 = pr2 - pc2;
      dsq = rp0*rp0 + rp1*rp1 + rp2*rp2;
    }
  }
  // wave 0 stages epilogue data (consumed only after the barrier)
  if (t < 64) {
    rel_lds[t][0] = rp0; rel_lds[t][1] = rp1; rel_lds[t][2] = rp2;
    col_sh[t] = cs;
  }

  // ---- issue ALL 16 table gathers up-front (deep MLP) ----
  uint4 va[4][2], vc[4][2];
  #pragma unroll
  for (int et = 0; et < 4; ++et) {
    const int src = et*16 + lc;
    int r_et = __shfl(erow, src, 64);
    int c_et = __shfl(ecol, src, 64);
    #pragma unroll
    for (int ti = 0; ti < 2; ++ti) {
      const int hb = (wv + 4*ti)*32 + quad*8;     // ushort offset in node row
      va[et][ti] = *(const uint4*)((const unsigned short*)Ar + (size_t)r_et*256 + hb);
      vc[et][ti] = *(const uint4*)((const unsigned short*)Ac + (size_t)c_et*256 + hb);
    }
  }

  // ---- per-wave constants ----
  const short8* __restrict__ w2x_f = (const short8*)wbuf;
  short8 a2w[4];
  #pragma unroll
  for (int ks = 0; ks < 4; ++ks) a2w[ks] = w2x_f[(wv*4 + ks)*64 + lane];

  float w1xd[2][4], w1pd[2][4], wp2[2][4], b2xr[4];
  #pragma unroll
  for (int ti = 0; ti < 2; ++ti)
    #pragma unroll
    for (int r = 0; r < 4; ++r) {
      int h = (wv + 4*ti)*16 + quad*4 + r;
      w1xd[ti][r] = W1x[16384 + h];     // dist^2 row (row 128 of [129][128])
      w1pd[ti][r] = W1p[16384 + h];
      wp2[ti][r]  = W2p[h];
    }
  #pragma unroll
  for (int r = 0; r < 4; ++r) b2xr[r] = b2x[wv*16 + quad*4 + r];
  const float b2ps = b2p[0];

  // ---- layer 1 process: silu -> H_lds; phi_p dot -> wsum ----
  #pragma unroll
  for (int et = 0; et < 4; ++et) {
    const float dsqv = __shfl(dsq, et*16 + lc, 64);
    float ps = 0.f;
    #pragma unroll
    for (int ti = 0; ti < 2; ++ti) {
      const int ht = wv + 4*ti;
      float sx[4];
      #pragma unroll
      for (int j = 0; j < 4; ++j) {
        unsigned a = (&va[et][ti].x)[j], bb = (&vc[et][ti].x)[j];
        float hx = __uint_as_float(a << 16) + __uint_as_float(bb << 16)
                 + dsqv * w1xd[ti][j];
        float hp = __uint_as_float(a & 0xffff0000u) + __uint_as_float(bb & 0xffff0000u)
                 + dsqv * w1pd[ti][j];
        sx[j] = silu(hx);
        ps += silu(hp) * wp2[ti][j];
      }
      *(uint2*)&H_lds[et*16 + lc][ht*16 + quad*4] =
          make_uint2(pk2bf(sx[0], sx[1]), pk2bf(sx[2], sx[3]));
    }
    ps += __shfl_xor(ps, 16, 64);
    ps += __shfl_xor(ps, 32, 64);
    if (lane < 16) wsum[wv][et*16 + lane] = ps;
  }
  __syncthreads();

  // ---- layer 2: MFMA + segmented-reduce scatter ----
  #pragma unroll 2
  for (int et = 0; et < 4; ++et) {
    floatx4 acc = {0,0,0,0};
    #pragma unroll
    for (int ks = 0; ks < 4; ++ks) {
      short8 b = *(const short8*)&H_lds[et*16 + lc][ks*32 + quad*8];
      acc = __builtin_amdgcn_mfma_f32_16x16x32_bf16(a2w[ks], b, acc, 0, 0, 0);
    }
    int edge = et*16 + lc;
    int myc = col_sh[edge];
    float v0 = acc[0] + b2xr[0], v1 = acc[1] + b2xr[1];
    float v2 = acc[2] + b2xr[2], v3 = acc[3] + b2xr[3];
    #pragma unroll
    for (int s = 1; s < 16; s <<= 1) {
      int   nc = __shfl_down(myc, s, 64);
      float n0 = __shfl_down(v0,  s, 64);
      float n1 = __shfl_down(v1,  s, 64);
      float n2 = __shfl_down(v2,  s, 64);
      float n3 = __shfl_down(v3,  s, 64);
      if ((lc + s < 16) && (nc == myc)) { v0 += n0; v1 += n1; v2 += n2; v3 += n3; }
    }
    bool head = (myc >= 0) && (lc == 0 || col_sh[edge-1] != myc);
    if (head) {
      float* dst = out_x + (size_t)myc*64 + wv*16 + quad*4;
      atomicAdd(dst + 0, v0);
      atomicAdd(dst + 1, v1);
      atomicAdd(dst + 2, v2);
      atomicAdd(dst + 3, v3);
    }
  }

  // ---- phi_p epilogue ----
  if (t < 64) {
    int c = col_sh[t];
    float w = wsum[0][t] + wsum[1][t] + wsum[2][t] + wsum[3][t] + b2ps;
    float p0 = w * rel_lds[t][0], p1 = w * rel_lds[t][1], p2 = w * rel_lds[t][2];
    #pragma unroll
    for (int s = 1; s < 64; s <<= 1) {
      int   nc = __shfl_down(c,  s, 64);
      float n0 = __shfl_down(p0, s, 64);
      float n1 = __shfl_down(p1, s, 64);
      float n2 = __shfl_down(p2, s, 64);
      if ((t + s < 64) && (nc == c)) { p0 += n0; p1 += n1; p2 += n2; }
    }
    bool head = (c >= 0) && (t == 0 || col_sh[t-1] != c);
    if (head) {
      atomicAdd(&out_pos[(size_t)c*3 + 0], p0);
      atomicAdd(&out_pos[(size_t)c*3 + 1], p1);
      atomicAdd(&out_pos[(size_t)c*3 + 2], p2);
    }
  }
}

extern "C" void kernel_launch(void* const* d_in, const int* in_sizes, int n_in,
                              void* d_out, int out_size, void* d_ws, size_t ws_size,
                              hipStream_t stream) {
  const float* x   = (const float*)d_in[0];
  const float* pos = (const float*)d_in[1];
  const int*   ei  = (const int*)d_in[2];
  const float* W1x = (const float*)d_in[3];
  const float* b1x = (const float*)d_in[4];
  const float* W2x = (const float*)d_in[5];
  const float* b2x = (const float*)d_in[6];
  const float* W1p = (const float*)d_in[7];
  const float* b1p = (const float*)d_in[8];
  const float* W2p = (const float*)d_in[9];
  const float* b2p = (const float*)d_in[10];

  const int E = in_sizes[2] / 2;        // 800000
  const int N = in_sizes[0] / 64;       // 50000
  const int* rowp = ei;
  const int* colp = ei + E;
  float* out_x   = (float*)d_out;
  float* out_pos = out_x + (size_t)N * 64;
  const int NB = (N + 1023) / 1024;     // 49

  // ws layout: [Ar][Ac][wbuf(W2 frags)][hist][bsum][sedge]
  char* ws = (char*)d_ws;
  const size_t tab_one = (size_t)N * 512;
  unsigned int*   Ar   = (unsigned int*)ws;
  unsigned int*   Ac   = (unsigned int*)(ws + tab_one);
  unsigned short* wbuf = (unsigned short*)(ws + 2*tab_one);
  int*  hist  = (int*)(ws + 2*tab_one + 16384);
  int*  bsum  = (int*)(ws + 2*tab_one + 16384 + 200192);
  int2* sedge = (int2*)(ws + 2*tab_one + 16384 + 200192 + 512);

  hipMemsetAsync(hist, 0, (size_t)N * sizeof(int), stream);

  // mega-setup: nodeA | zero d_out | histogram | repack W2x
  const int nb_node = (N + 63) / 64;                 // 782
  const int nb_zero = (out_size + 4095) / 4096;      // 818
  const int nb_hist = ((E >> 2) + 255) / 256;        // 782
  const int nb_rep  = 32;
  const int b1 = nb_node, b2 = b1 + nb_zero, b3 = b2 + nb_hist;
  k_mega<<<b3 + nb_rep, 256, 0, stream>>>(
      (float*)d_out, out_size, colp, E, hist, x, N,
      W1x, W1p, W2x, b1x, b1p, wbuf, Ar, Ac, b1, b2, b3);

  k_scan_a<<<NB, 256, 0, stream>>>(hist, N, bsum);
  k_scatter<<<((E >> 2) + 255) / 256, 256, 0, stream>>>(
      rowp, colp, E, hist, bsum, NB, sedge);

  mp_main<<<(E + 63) / 64, 256, 0, stream>>>(
      pos, sedge, E, Ar, Ac, W1x, W1p, b2x, W2p, b2p, wbuf, out_x, out_pos);
}

// Round 13
// 326.334 us; speedup vs baseline: 1.0390x; 1.0126x over previous
//
#include <hip/hip_runtime.h>

typedef short short8 __attribute__((ext_vector_type(8)));
typedef float floatx4 __attribute__((ext_vector_type(4)));

__device__ __forceinline__ unsigned short f2bf(float f) {
  unsigned int u = __float_as_uint(f);
  u += 0x7FFFu + ((u >> 16) & 1u);   // RNE
  return (unsigned short)(u >> 16);
}

#if __has_builtin(__builtin_amdgcn_cvt_pk_bf16_f32)
typedef __bf16 bf16x2_t __attribute__((ext_vector_type(2)));
__device__ __forceinline__ unsigned int pk2bf(float lo, float hi) {
  bf16x2_t v = __builtin_amdgcn_cvt_pk_bf16_f32(lo, hi);
  return __builtin_bit_cast(unsigned int, v);
}
#else
__device__ __forceinline__ unsigned int pk2bf(float lo, float hi) {
  return (unsigned)f2bf(lo) | ((unsigned)f2bf(hi) << 16);
}
#endif

__device__ __forceinline__ float silu(float h) {
  return h * __builtin_amdgcn_rcpf(1.f + __expf(-h));
}

// ---------------------------------------------------------------------------
// Mega-setup (R10, unchanged): nodeA tables | zero d_out | histogram | W2x
// repack. Ar[n][h] = x[n]·W1[0:64,h]+b1[h]; Ac[n][h] = x[n]·W1[64:128,h];
// packed per h: uint = (x_bf16 | p_bf16<<16).
// ---------------------------------------------------------------------------
__global__ __launch_bounds__(256) void k_mega(
    float* __restrict__ out, int out_n,
    const int* __restrict__ colp, int E, int* __restrict__ hist,
    const float* __restrict__ x, int N,
    const float* __restrict__ W1x, const float* __restrict__ W1p,
    const float* __restrict__ W2x,
    const float* __restrict__ b1x, const float* __restrict__ b1p,
    unsigned short* __restrict__ wbuf,
    unsigned int* __restrict__ Ar, unsigned int* __restrict__ Ac,
    int b1, int b2, int b3)
{
  __shared__ __align__(16) unsigned short xt[64][72];
  const int blk = blockIdx.x, t = threadIdx.x;

  if (blk < b1) {
    // ---------------- job nodeA ----------------
    const int n0 = blk * 64;
    const int wv = t >> 6, lane = t & 63, quad = lane >> 4, lc = lane & 15;

    {  // stage x tile (bf16)
      int nd = t >> 2, p = t & 3;
      int n = n0 + nd;
      uint4 o0, o1;
      if (n < N) {
        const float4* xp = (const float4*)(x + (size_t)n*64 + p*16);
        float4 a = xp[0], b = xp[1], c = xp[2], d = xp[3];
        o0 = make_uint4(pk2bf(a.x,a.y), pk2bf(a.z,a.w), pk2bf(b.x,b.y), pk2bf(b.z,b.w));
        o1 = make_uint4(pk2bf(c.x,c.y), pk2bf(c.z,c.w), pk2bf(d.x,d.y), pk2bf(d.z,d.w));
      } else {
        o0 = o1 = make_uint4(0u,0u,0u,0u);
      }
      *(uint4*)&xt[nd][p*16]     = o0;
      *(uint4*)&xt[nd][p*16 + 8] = o1;
    }

    // inline W1 fragment conversion from f32 (L2-hot)
    short8 fxr[2][2], fxc[2][2], fpr[2][2], fpc[2][2];
    float bxv[2][4], bpv[2][4];
    #pragma unroll
    for (int ti = 0; ti < 2; ++ti) {
      const int nt = wv + 4*ti;
      const int n  = nt*16 + lc;
      #pragma unroll
      for (int k2 = 0; k2 < 2; ++k2) {
        #pragma unroll
        for (int j = 0; j < 8; ++j) {
          const int kr = k2*32 + quad*8 + j;          // 0..63
          fxr[ti][k2][j] = (short)f2bf(W1x[kr*128 + n]);
          fxc[ti][k2][j] = (short)f2bf(W1x[(64 + kr)*128 + n]);
          fpr[ti][k2][j] = (short)f2bf(W1p[kr*128 + n]);
          fpc[ti][k2][j] = (short)f2bf(W1p[(64 + kr)*128 + n]);
        }
      }
      #pragma unroll
      for (int r = 0; r < 4; ++r) {
        bxv[ti][r] = b1x[nt*16 + quad*4 + r];
        bpv[ti][r] = b1p[nt*16 + quad*4 + r];
      }
    }
    __syncthreads();

    #pragma unroll 1
    for (int mw = 0; mw < 4; ++mw) {
      short8 bb0 = *(const short8*)&xt[mw*16 + lc][quad*8];       // k 0..31
      short8 bb1 = *(const short8*)&xt[mw*16 + lc][32 + quad*8];  // k 32..63
      const int nd = n0 + mw*16 + lc;
      #pragma unroll
      for (int ti = 0; ti < 2; ++ti) {
        floatx4 xr = {0,0,0,0}, xc = {0,0,0,0}, pr = {0,0,0,0}, pc = {0,0,0,0};
        xr = __builtin_amdgcn_mfma_f32_16x16x32_bf16(fxr[ti][0], bb0, xr, 0,0,0);
        xr = __builtin_amdgcn_mfma_f32_16x16x32_bf16(fxr[ti][1], bb1, xr, 0,0,0);
        xc = __builtin_amdgcn_mfma_f32_16x16x32_bf16(fxc[ti][0], bb0, xc, 0,0,0);
        xc = __builtin_amdgcn_mfma_f32_16x16x32_bf16(fxc[ti][1], bb1, xc, 0,0,0);
        pr = __builtin_amdgcn_mfma_f32_16x16x32_bf16(fpr[ti][0], bb0, pr, 0,0,0);
        pr = __builtin_amdgcn_mfma_f32_16x16x32_bf16(fpr[ti][1], bb1, pr, 0,0,0);
        pc = __builtin_amdgcn_mfma_f32_16x16x32_bf16(fpc[ti][0], bb0, pc, 0,0,0);
        pc = __builtin_amdgcn_mfma_f32_16x16x32_bf16(fpc[ti][1], bb1, pc, 0,0,0);
        if (nd < N) {
          const int hbase = (wv + 4*ti)*16 + quad*4;
          uint4 ur = make_uint4(pk2bf(xr[0]+bxv[ti][0], pr[0]+bpv[ti][0]),
                                pk2bf(xr[1]+bxv[ti][1], pr[1]+bpv[ti][1]),
                                pk2bf(xr[2]+bxv[ti][2], pr[2]+bpv[ti][2]),
                                pk2bf(xr[3]+bxv[ti][3], pr[3]+bpv[ti][3]));
          uint4 uc = make_uint4(pk2bf(xc[0], pc[0]), pk2bf(xc[1], pc[1]),
                                pk2bf(xc[2], pc[2]), pk2bf(xc[3], pc[3]));
          *(uint4*)(Ar + (size_t)nd*128 + hbase) = ur;
          *(uint4*)(Ac + (size_t)nd*128 + hbase) = uc;
        }
      }
    }
  } else if (blk < b2) {
    // ---------------- job zero d_out ----------------
    int i = ((blk - b1) * 256 + t) * 16;
    #pragma unroll
    for (int q = 0; q < 4; ++q) {
      int j = i + q*4;
      if (j + 4 <= out_n) *(float4*)(out + j) = make_float4(0.f,0.f,0.f,0.f);
      else for (int k = j; k < out_n; ++k) out[k] = 0.f;
    }
  } else if (blk < b3) {
    // ---------------- job histogram ----------------
    int i4 = (blk - b2) * 256 + t;
    if (i4 < (E >> 2)) {
      int4 c = *(const int4*)(colp + i4*4);
      atomicAdd(&hist[c.x], 1); atomicAdd(&hist[c.y], 1);
      atomicAdd(&hist[c.z], 1); atomicAdd(&hist[c.w], 1);
    }
    if (blk == b2 && t == 0)
      for (int k = E & ~3; k < E; ++k) atomicAdd(&hist[colp[k]], 1);
  } else {
    // ---------------- job repack W2x ----------------
    int i = (blk - b3) * 256 + t;
    if (i < 8192) {
      int jj = i & 7, lane = (i >> 3) & 63, ks = (i >> 9) & 3, nt = (i >> 11) & 3;
      int k = ks*32 + (lane >> 4)*8 + jj;
      wbuf[i] = f2bf(W2x[k*64 + nt*16 + (lane & 15)]);
    }
  }
}

// ---------------------------------------------------------------------------
// Counting-sort scan (49 blocks)
// ---------------------------------------------------------------------------
__global__ __launch_bounds__(256) void k_scan_a(
    int* __restrict__ hist, int N, int* __restrict__ bsum) {
  __shared__ int wtot[4], wexc[4];
  int t = threadIdx.x, lane = t & 63, w = t >> 6;
  int base = blockIdx.x * 1024 + t * 4;
  int v0 = (base + 0 < N) ? hist[base + 0] : 0;
  int v1 = (base + 1 < N) ? hist[base + 1] : 0;
  int v2 = (base + 2 < N) ? hist[base + 2] : 0;
  int v3 = (base + 3 < N) ? hist[base + 3] : 0;
  int T = v0 + v1 + v2 + v3;
  int inc = T;
  #pragma unroll
  for (int s = 1; s < 64; s <<= 1) {
    int u = __shfl_up(inc, s, 64);
    if (lane >= s) inc += u;
  }
  if (lane == 63) wtot[w] = inc;
  __syncthreads();
  if (t == 0) {
    int a = 0;
    #pragma unroll
    for (int i = 0; i < 4; ++i) { wexc[i] = a; a += wtot[i]; }
    bsum[blockIdx.x] = a;
  }
  __syncthreads();
  int tex = wexc[w] + (inc - T);
  if (base + 0 < N) hist[base + 0] = tex;
  if (base + 1 < N) hist[base + 1] = tex + v0;
  if (base + 2 < N) hist[base + 2] = tex + v0 + v1;
  if (base + 3 < N) hist[base + 3] = tex + v0 + v1 + v2;
}

// ---------------------------------------------------------------------------
// Scatter (4 edges/thread) with inline top-scan of bsum (NB<=64)
// ---------------------------------------------------------------------------
__global__ __launch_bounds__(256) void k_scatter(
    const int* __restrict__ row, const int* __restrict__ col, int E,
    int* __restrict__ excl, const int* __restrict__ bsum, int NB,
    int2* __restrict__ sedge) {
  __shared__ int boff_sh[64];
  int t = threadIdx.x;
  if (t < 64) {
    int v = (t < NB) ? bsum[t] : 0;
    int inc = v;
    #pragma unroll
    for (int s = 1; s < 64; s <<= 1) {
      int u = __shfl_up(inc, s, 64);
      if (t >= s) inc += u;
    }
    boff_sh[t] = inc - v;
  }
  __syncthreads();
  int i4 = blockIdx.x * 256 + t;
  if (i4 < (E >> 2)) {
    int4 c = *(const int4*)(col + i4*4);
    int4 r = *(const int4*)(row + i4*4);
    int p;
    p = atomicAdd(&excl[c.x], 1) + boff_sh[c.x >> 10]; sedge[p] = make_int2(r.x, c.x);
    p = atomicAdd(&excl[c.y], 1) + boff_sh[c.y >> 10]; sedge[p] = make_int2(r.y, c.y);
    p = atomicAdd(&excl[c.z], 1) + boff_sh[c.z >> 10]; sedge[p] = make_int2(r.z, c.z);
    p = atomicAdd(&excl[c.w], 1) + boff_sh[c.w >> 10]; sedge[p] = make_int2(r.w, c.w);
  }
  if (blockIdx.x == 0 && t == 0) {
    for (int k = E & ~3; k < E; ++k) {
      int c = col[k];
      int p = atomicAdd(&excl[c], 1) + boff_sh[c >> 10];
      sedge[p] = make_int2(row[k], c);
    }
  }
}

// ---------------------------------------------------------------------------
// Main kernel — wave-autonomous: each 64-lane wave owns 16 sorted edges.
// Lane (quad,lc): edge lc, h-range {ks*32 + quad*8 + j}. Layer-1 silu
// outputs ARE the layer-2 B-fragment (B[k][n]: n=lane&15, k=quad*8+j per
// 32-slice) -> H stays in registers; NO LDS, NO barriers, no inter-wave
// coupling. 4 independent waves per 256-thread block. Segmented suffix-sum
// per 16-lane group (same head semantics as R10's per-et groups).
// ---------------------------------------------------------------------------
__global__ __launch_bounds__(256) void mp_main(
    const float* __restrict__ pos,
    const int2* __restrict__ sedge, int E,
    const unsigned int* __restrict__ Ar, const unsigned int* __restrict__ Ac,
    const float* __restrict__ W1x, const float* __restrict__ W1p,
    const float* __restrict__ b2x, const float* __restrict__ W2p,
    const float* __restrict__ b2p,
    const unsigned short* __restrict__ wbuf,
    float* __restrict__ out_x, float* __restrict__ out_pos)
{
  const int t    = threadIdx.x;
  const int wv   = t >> 6;
  const int lane = t & 63;
  const int quad = lane >> 4;
  const int lc   = lane & 15;
  const int e0   = blockIdx.x * 64 + wv * 16;   // this wave's 16 edges

  // ---- edge data: lane -> edge e0+lc (quad-redundant, address-identical
  //      -> coalesced broadcast loads) ----
  int ecol = -1, grow = 0, gcol = 0;
  float dsq = 0.f, rp0 = 0.f, rp1 = 0.f, rp2 = 0.f;
  {
    int e = e0 + lc;
    if (e < E) {
      int2 rc = sedge[e];
      grow = rc.x; gcol = rc.y; ecol = rc.y;
      float pr0 = pos[grow*3+0], pr1 = pos[grow*3+1], pr2 = pos[grow*3+2];
      float pc0 = pos[gcol*3+0], pc1 = pos[gcol*3+1], pc2 = pos[gcol*3+2];
      rp0 = pr0 - pc0; rp1 = pr1 - pc1; rp2 = pr2 - pc2;
      dsq = rp0*rp0 + rp1*rp1 + rp2*rp2;
    }
  }
  // prev col within the 16-lane group (head detection; lc==0 is always head)
  const int prevc = __shfl(ecol, lane - 1, 64);   // used only when lc>0

  // ---- issue ALL 16 table gathers up-front (deep MLP) ----
  const unsigned int* arow = Ar + (size_t)grow * 128 + quad * 8;
  const unsigned int* acol = Ac + (size_t)gcol * 128 + quad * 8;
  uint4 ga[4][2], gc[4][2];
  #pragma unroll
  for (int ks = 0; ks < 4; ++ks) {
    ga[ks][0] = *(const uint4*)(arow + ks*32);
    ga[ks][1] = *(const uint4*)(arow + ks*32 + 4);
    gc[ks][0] = *(const uint4*)(acol + ks*32);
    gc[ks][1] = *(const uint4*)(acol + ks*32 + 4);
  }

  // ---- layer 1: silu -> register B-fragments; phi_p dot ----
  short8 bfr[4];
  float ps = 0.f;
  #pragma unroll
  for (int ks = 0; ks < 4; ++ks) {
    const int hb = ks*32 + quad*8;
    float4 wx0 = *(const float4*)(W1x + 16384 + hb);      // dist^2 row
    float4 wx1 = *(const float4*)(W1x + 16384 + hb + 4);
    float4 wp0 = *(const float4*)(W1p + 16384 + hb);
    float4 wp1 = *(const float4*)(W1p + 16384 + hb + 4);
    float4 w20 = *(const float4*)(W2p + hb);
    float4 w21 = *(const float4*)(W2p + hb + 4);
    float sx[8];
    #pragma unroll
    for (int j = 0; j < 8; ++j) {
      unsigned a = (j < 4) ? (&ga[ks][0].x)[j] : (&ga[ks][1].x)[j-4];
      unsigned c = (j < 4) ? (&gc[ks][0].x)[j] : (&gc[ks][1].x)[j-4];
      float wxd = (j < 4) ? (&wx0.x)[j] : (&wx1.x)[j-4];
      float wpd = (j < 4) ? (&wp0.x)[j] : (&wp1.x)[j-4];
      float w2v = (j < 4) ? (&w20.x)[j] : (&w21.x)[j-4];
      float hx = __uint_as_float(a << 16) + __uint_as_float(c << 16) + dsq * wxd;
      float hp = __uint_as_float(a & 0xffff0000u) + __uint_as_float(c & 0xffff0000u)
               + dsq * wpd;
      sx[j] = silu(hx);
      ps += silu(hp) * w2v;
    }
    uint4 pk = make_uint4(pk2bf(sx[0], sx[1]), pk2bf(sx[2], sx[3]),
                          pk2bf(sx[4], sx[5]), pk2bf(sx[6], sx[7]));
    bfr[ks] = __builtin_bit_cast(short8, pk);
  }
  ps += __shfl_xor(ps, 16, 64);   // combine quads -> full phi_p dot per edge
  ps += __shfl_xor(ps, 32, 64);

  // ---- layer 2: 4 f-tiles x 4 ks MFMA from registers + segmented scatter --
  const short8* __restrict__ w2x_f = (const short8*)wbuf;
  #pragma unroll
  for (int ft = 0; ft < 4; ++ft) {
    floatx4 acc = {0,0,0,0};
    #pragma unroll
    for (int ks = 0; ks < 4; ++ks)
      acc = __builtin_amdgcn_mfma_f32_16x16x32_bf16(
                w2x_f[(ft*4 + ks)*64 + lane], bfr[ks], acc, 0, 0, 0);
    const float4 b2v = *(const float4*)(b2x + ft*16 + quad*4);
    int myc = ecol;
    float v0 = acc[0] + b2v.x, v1 = acc[1] + b2v.y;
    float v2 = acc[2] + b2v.z, v3 = acc[3] + b2v.w;
    #pragma unroll
    for (int s = 1; s < 16; s <<= 1) {
      int   nc = __shfl_down(myc, s, 64);
      float n0 = __shfl_down(v0,  s, 64);
      float n1 = __shfl_down(v1,  s, 64);
      float n2 = __shfl_down(v2,  s, 64);
      float n3 = __shfl_down(v3,  s, 64);
      if ((lc + s < 16) && (nc == myc)) { v0 += n0; v1 += n1; v2 += n2; v3 += n3; }
    }
    bool head = (myc >= 0) && (lc == 0 || prevc != myc);
    if (head) {
      float* dst = out_x + (size_t)myc*64 + ft*16 + quad*4;
      atomicAdd(dst + 0, v0);
      atomicAdd(dst + 1, v1);
      atomicAdd(dst + 2, v2);
      atomicAdd(dst + 3, v3);
    }
  }

  // ---- phi_p epilogue: weight * rel_pos, segmented over 16 edges ----
  {
    float w  = ps + b2p[0];
    float p0 = w * rp0, p1 = w * rp1, p2 = w * rp2;
    int   c  = ecol;
    #pragma unroll
    for (int s = 1; s < 16; s <<= 1) {
      int   nc = __shfl_down(c,  s, 64);
      float n0 = __shfl_down(p0, s, 64);
      float n1 = __shfl_down(p1, s, 64);
      float n2 = __shfl_down(p2, s, 64);
      if ((lc + s < 16) && (nc == c)) { p0 += n0; p1 += n1; p2 += n2; }
    }
    bool head = (c >= 0) && (quad == 0) && (lc == 0 || prevc != c);
    if (head) {
      atomicAdd(&out_pos[(size_t)c*3 + 0], p0);
      atomicAdd(&out_pos[(size_t)c*3 + 1], p1);
      atomicAdd(&out_pos[(size_t)c*3 + 2], p2);
    }
  }
}

extern "C" void kernel_launch(void* const* d_in, const int* in_sizes, int n_in,
                              void* d_out, int out_size, void* d_ws, size_t ws_size,
                              hipStream_t stream) {
  const float* x   = (const float*)d_in[0];
  const float* pos = (const float*)d_in[1];
  const int*   ei  = (const int*)d_in[2];
  const float* W1x = (const float*)d_in[3];
  const float* b1x = (const float*)d_in[4];
  const float* W2x = (const float*)d_in[5];
  const float* b2x = (const float*)d_in[6];
  const float* W1p = (const float*)d_in[7];
  const float* b1p = (const float*)d_in[8];
  const float* W2p = (const float*)d_in[9];
  const float* b2p = (const float*)d_in[10];

  const int E = in_sizes[2] / 2;        // 800000
  const int N = in_sizes[0] / 64;       // 50000
  const int* rowp = ei;
  const int* colp = ei + E;
  float* out_x   = (float*)d_out;
  float* out_pos = out_x + (size_t)N * 64;
  const int NB = (N + 1023) / 1024;     // 49

  // ws layout: [Ar][Ac][wbuf(W2 frags)][hist][bsum][sedge]
  char* ws = (char*)d_ws;
  const size_t tab_one = (size_t)N * 512;
  unsigned int*   Ar   = (unsigned int*)ws;
  unsigned int*   Ac   = (unsigned int*)(ws + tab_one);
  unsigned short* wbuf = (unsigned short*)(ws + 2*tab_one);
  int*  hist  = (int*)(ws + 2*tab_one + 16384);
  int*  bsum  = (int*)(ws + 2*tab_one + 16384 + 200192);
  int2* sedge = (int2*)(ws + 2*tab_one + 16384 + 200192 + 512);

  hipMemsetAsync(hist, 0, (size_t)N * sizeof(int), stream);

  // mega-setup: nodeA | zero d_out | histogram | repack W2x
  const int nb_node = (N + 63) / 64;                 // 782
  const int nb_zero = (out_size + 4095) / 4096;      // 818
  const int nb_hist = ((E >> 2) + 255) / 256;        // 782
  const int nb_rep  = 32;
  const int b1 = nb_node, b2 = b1 + nb_zero, b3 = b2 + nb_hist;
  k_mega<<<b3 + nb_rep, 256, 0, stream>>>(
      (float*)d_out, out_size, colp, E, hist, x, N,
      W1x, W1p, W2x, b1x, b1p, wbuf, Ar, Ac, b1, b2, b3);

  k_scan_a<<<NB, 256, 0, stream>>>(hist, N, bsum);
  k_scatter<<<((E >> 2) + 255) / 256, 256, 0, stream>>>(
      rowp, colp, E, hist, bsum, NB, sedge);

  mp_main<<<(E + 63) / 64, 256, 0, stream>>>(
      pos, sedge, E, Ar, Ac, W1x, W1p, b2x, W2p, b2p, wbuf, out_x, out_pos);
}

// Round 14
// 311.998 us; speedup vs baseline: 1.0867x; 1.0459x over previous
//
#include <hip/hip_runtime.h>

typedef short short8 __attribute__((ext_vector_type(8)));
typedef float floatx4 __attribute__((ext_vector_type(4)));

__device__ __forceinline__ unsigned short f2bf(float f) {
  unsigned int u = __float_as_uint(f);
  u += 0x7FFFu + ((u >> 16) & 1u);   // RNE
  return (unsigned short)(u >> 16);
}

#if __has_builtin(__builtin_amdgcn_cvt_pk_bf16_f32)
typedef __bf16 bf16x2_t __attribute__((ext_vector_type(2)));
__device__ __forceinline__ unsigned int pk2bf(float lo, float hi) {
  bf16x2_t v = __builtin_amdgcn_cvt_pk_bf16_f32(lo, hi);
  return __builtin_bit_cast(unsigned int, v);
}
#else
__device__ __forceinline__ unsigned int pk2bf(float lo, float hi) {
  return (unsigned)f2bf(lo) | ((unsigned)f2bf(hi) << 16);
}
#endif

__device__ __forceinline__ float silu(float h) {
  return h * __builtin_amdgcn_rcpf(1.f + __expf(-h));
}

// ---------------------------------------------------------------------------
// Mega-setup (one dispatch, independent jobs by block range): nodeA tables |
// zero d_out | col histogram | W2x repack. (Layout notes in R10.)
// ---------------------------------------------------------------------------
__global__ __launch_bounds__(256) void k_mega(
    float* __restrict__ out, int out_n,
    const int* __restrict__ colp, int E, int* __restrict__ hist,
    const float* __restrict__ x, int N,
    const float* __restrict__ W1x, const float* __restrict__ W1p,
    const float* __restrict__ W2x,
    const float* __restrict__ b1x, const float* __restrict__ b1p,
    unsigned short* __restrict__ wbuf,
    unsigned int* __restrict__ Ar, unsigned int* __restrict__ Ac,
    int b1, int b2, int b3)
{
  __shared__ __align__(16) unsigned short xt[64][72];
  const int blk = blockIdx.x, t = threadIdx.x;

  if (blk < b1) {
    // ---------------- job nodeA ----------------
    const int n0 = blk * 64;
    const int wv = t >> 6, lane = t & 63, quad = lane >> 4, lc = lane & 15;

    {  // stage x tile (bf16)
      int nd = t >> 2, p = t & 3;
      int n = n0 + nd;
      uint4 o0, o1;
      if (n < N) {
        const float4* xp = (const float4*)(x + (size_t)n*64 + p*16);
        float4 a = xp[0], b = xp[1], c = xp[2], d = xp[3];
        o0 = make_uint4(pk2bf(a.x,a.y), pk2bf(a.z,a.w), pk2bf(b.x,b.y), pk2bf(b.z,b.w));
        o1 = make_uint4(pk2bf(c.x,c.y), pk2bf(c.z,c.w), pk2bf(d.x,d.y), pk2bf(d.z,d.w));
      } else {
        o0 = o1 = make_uint4(0u,0u,0u,0u);
      }
      *(uint4*)&xt[nd][p*16]     = o0;
      *(uint4*)&xt[nd][p*16 + 8] = o1;
    }

    // inline W1 fragment conversion from f32 (L2-hot)
    short8 fxr[2][2], fxc[2][2], fpr[2][2], fpc[2][2];
    float bxv[2][4], bpv[2][4];
    #pragma unroll
    for (int ti = 0; ti < 2; ++ti) {
      const int nt = wv + 4*ti;
      const int n  = nt*16 + lc;
      #pragma unroll
      for (int k2 = 0; k2 < 2; ++k2) {
        #pragma unroll
        for (int j = 0; j < 8; ++j) {
          const int kr = k2*32 + quad*8 + j;          // 0..63
          fxr[ti][k2][j] = (short)f2bf(W1x[kr*128 + n]);
          fxc[ti][k2][j] = (short)f2bf(W1x[(64 + kr)*128 + n]);
          fpr[ti][k2][j] = (short)f2bf(W1p[kr*128 + n]);
          fpc[ti][k2][j] = (short)f2bf(W1p[(64 + kr)*128 + n]);
        }
      }
      #pragma unroll
      for (int r = 0; r < 4; ++r) {
        bxv[ti][r] = b1x[nt*16 + quad*4 + r];
        bpv[ti][r] = b1p[nt*16 + quad*4 + r];
      }
    }
    __syncthreads();

    #pragma unroll 1
    for (int mw = 0; mw < 4; ++mw) {
      short8 bb0 = *(const short8*)&xt[mw*16 + lc][quad*8];       // k 0..31
      short8 bb1 = *(const short8*)&xt[mw*16 + lc][32 + quad*8];  // k 32..63
      const int nd = n0 + mw*16 + lc;
      #pragma unroll
      for (int ti = 0; ti < 2; ++ti) {
        floatx4 xr = {0,0,0,0}, xc = {0,0,0,0}, pr = {0,0,0,0}, pc = {0,0,0,0};
        xr = __builtin_amdgcn_mfma_f32_16x16x32_bf16(fxr[ti][0], bb0, xr, 0,0,0);
        xr = __builtin_amdgcn_mfma_f32_16x16x32_bf16(fxr[ti][1], bb1, xr, 0,0,0);
        xc = __builtin_amdgcn_mfma_f32_16x16x32_bf16(fxc[ti][0], bb0, xc, 0,0,0);
        xc = __builtin_amdgcn_mfma_f32_16x16x32_bf16(fxc[ti][1], bb1, xc, 0,0,0);
        pr = __builtin_amdgcn_mfma_f32_16x16x32_bf16(fpr[ti][0], bb0, pr, 0,0,0);
        pr = __builtin_amdgcn_mfma_f32_16x16x32_bf16(fpr[ti][1], bb1, pr, 0,0,0);
        pc = __builtin_amdgcn_mfma_f32_16x16x32_bf16(fpc[ti][0], bb0, pc, 0,0,0);
        pc = __builtin_amdgcn_mfma_f32_16x16x32_bf16(fpc[ti][1], bb1, pc, 0,0,0);
        if (nd < N) {
          const int hbase = (wv + 4*ti)*16 + quad*4;
          uint4 ur = make_uint4(pk2bf(xr[0]+bxv[ti][0], pr[0]+bpv[ti][0]),
                                pk2bf(xr[1]+bxv[ti][1], pr[1]+bpv[ti][1]),
                                pk2bf(xr[2]+bxv[ti][2], pr[2]+bpv[ti][2]),
                                pk2bf(xr[3]+bxv[ti][3], pr[3]+bpv[ti][3]));
          uint4 uc = make_uint4(pk2bf(xc[0], pc[0]), pk2bf(xc[1], pc[1]),
                                pk2bf(xc[2], pc[2]), pk2bf(xc[3], pc[3]));
          *(uint4*)(Ar + (size_t)nd*128 + hbase) = ur;
          *(uint4*)(Ac + (size_t)nd*128 + hbase) = uc;
        }
      }
    }
  } else if (blk < b2) {
    // ---------------- job zero d_out ----------------
    int i = ((blk - b1) * 256 + t) * 16;
    #pragma unroll
    for (int q = 0; q < 4; ++q) {
      int j = i + q*4;
      if (j + 4 <= out_n) *(float4*)(out + j) = make_float4(0.f,0.f,0.f,0.f);
      else for (int k = j; k < out_n; ++k) out[k] = 0.f;
    }
  } else if (blk < b3) {
    // ---------------- job histogram ----------------
    int i4 = (blk - b2) * 256 + t;
    if (i4 < (E >> 2)) {
      int4 c = *(const int4*)(colp + i4*4);
      atomicAdd(&hist[c.x], 1); atomicAdd(&hist[c.y], 1);
      atomicAdd(&hist[c.z], 1); atomicAdd(&hist[c.w], 1);
    }
    if (blk == b2 && t == 0)
      for (int k = E & ~3; k < E; ++k) atomicAdd(&hist[colp[k]], 1);
  } else {
    // ---------------- job repack W2x ----------------
    int i = (blk - b3) * 256 + t;
    if (i < 8192) {
      int jj = i & 7, lane = (i >> 3) & 63, ks = (i >> 9) & 3, nt = (i >> 11) & 3;
      int k = ks*32 + (lane >> 4)*8 + jj;
      wbuf[i] = f2bf(W2x[k*64 + nt*16 + (lane & 15)]);
    }
  }
}

// ---------------------------------------------------------------------------
// Counting-sort scan (49 blocks)
// ---------------------------------------------------------------------------
__global__ __launch_bounds__(256) void k_scan_a(
    int* __restrict__ hist, int N, int* __restrict__ bsum) {
  __shared__ int wtot[4], wexc[4];
  int t = threadIdx.x, lane = t & 63, w = t >> 6;
  int base = blockIdx.x * 1024 + t * 4;
  int v0 = (base + 0 < N) ? hist[base + 0] : 0;
  int v1 = (base + 1 < N) ? hist[base + 1] : 0;
  int v2 = (base + 2 < N) ? hist[base + 2] : 0;
  int v3 = (base + 3 < N) ? hist[base + 3] : 0;
  int T = v0 + v1 + v2 + v3;
  int inc = T;
  #pragma unroll
  for (int s = 1; s < 64; s <<= 1) {
    int u = __shfl_up(inc, s, 64);
    if (lane >= s) inc += u;
  }
  if (lane == 63) wtot[w] = inc;
  __syncthreads();
  if (t == 0) {
    int a = 0;
    #pragma unroll
    for (int i = 0; i < 4; ++i) { wexc[i] = a; a += wtot[i]; }
    bsum[blockIdx.x] = a;
  }
  __syncthreads();
  int tex = wexc[w] + (inc - T);
  if (base + 0 < N) hist[base + 0] = tex;
  if (base + 1 < N) hist[base + 1] = tex + v0;
  if (base + 2 < N) hist[base + 2] = tex + v0 + v1;
  if (base + 3 < N) hist[base + 3] = tex + v0 + v1 + v2;
}

// ---------------------------------------------------------------------------
// Scatter (4 edges/thread) with inline top-scan of bsum (NB<=64)
// ---------------------------------------------------------------------------
__global__ __launch_bounds__(256) void k_scatter(
    const int* __restrict__ row, const int* __restrict__ col, int E,
    int* __restrict__ excl, const int* __restrict__ bsum, int NB,
    int2* __restrict__ sedge) {
  __shared__ int boff_sh[64];
  int t = threadIdx.x;
  if (t < 64) {
    int v = (t < NB) ? bsum[t] : 0;
    int inc = v;
    #pragma unroll
    for (int s = 1; s < 64; s <<= 1) {
      int u = __shfl_up(inc, s, 64);
      if (t >= s) inc += u;
    }
    boff_sh[t] = inc - v;
  }
  __syncthreads();
  int i4 = blockIdx.x * 256 + t;
  if (i4 < (E >> 2)) {
    int4 c = *(const int4*)(col + i4*4);
    int4 r = *(const int4*)(row + i4*4);
    int p;
    p = atomicAdd(&excl[c.x], 1) + boff_sh[c.x >> 10]; sedge[p] = make_int2(r.x, c.x);
    p = atomicAdd(&excl[c.y], 1) + boff_sh[c.y >> 10]; sedge[p] = make_int2(r.y, c.y);
    p = atomicAdd(&excl[c.z], 1) + boff_sh[c.z >> 10]; sedge[p] = make_int2(r.z, c.z);
    p = atomicAdd(&excl[c.w], 1) + boff_sh[c.w >> 10]; sedge[p] = make_int2(r.w, c.w);
  }
  if (blockIdx.x == 0 && t == 0) {
    for (int k = E & ~3; k < E; ++k) {
      int c = col[k];
      int p = atomicAdd(&excl[c], 1) + boff_sh[c >> 10];
      sedge[p] = make_int2(row[k], c);
    }
  }
}

// ---------------------------------------------------------------------------
// Main kernel — R10 structure (135 us proven): 64 sorted edges/block,
// 256 threads. ONLY change vs R10: layer-1 et-loop fully unrolled so the
// compiler hoists all 16 table gathers ahead of the first silu (deep MLP
// on the winning skeleton). Layer 2 + epilogue byte-identical.
// ---------------------------------------------------------------------------
__global__ __launch_bounds__(256) void mp_main(
    const float* __restrict__ pos,
    const int2* __restrict__ sedge, int E,
    const unsigned int* __restrict__ Ar, const unsigned int* __restrict__ Ac,
    const float* __restrict__ W1x, const float* __restrict__ W1p,
    const float* __restrict__ b2x, const float* __restrict__ W2p,
    const float* __restrict__ b2p,
    const unsigned short* __restrict__ wbuf,
    float* __restrict__ out_x, float* __restrict__ out_pos)
{
  __shared__ __align__(16) unsigned short H_lds[64][136];  // 17408 B
  __shared__ __align__(16) uint4 edata[64];                // {row, col, dsq, 0}
  __shared__ float rel_lds[64][3];
  __shared__ int   col_sh[64];
  __shared__ float wsum[4][64];

  const int t    = threadIdx.x;
  const int e0   = blockIdx.x * 64;
  const int wv   = t >> 6;
  const int lane = t & 63;
  const int quad = lane >> 4;
  const int lc   = lane & 15;

  if (t < 64) {
    int e = e0 + t;
    int r = 0, c = 0, cs = -1;
    float rp0 = 0.f, rp1 = 0.f, rp2 = 0.f, dsq = 0.f;
    if (e < E) {
      int2 rc = sedge[e]; r = rc.x; c = rc.y;
      cs = c;
      float pr0 = pos[r*3+0], pr1 = pos[r*3+1], pr2 = pos[r*3+2];
      float pc0 = pos[c*3+0], pc1 = pos[c*3+1], pc2 = pos[c*3+2];
      rp0 = pr0 - pc0; rp1 = pr1 - pc1; rp2 = pr2 - pc2;
      dsq = rp0*rp0 + rp1*rp1 + rp2*rp2;
    }
    rel_lds[t][0] = rp0; rel_lds[t][1] = rp1; rel_lds[t][2] = rp2;
    col_sh[t] = cs;
    edata[t] = make_uint4((unsigned)r, (unsigned)c, __float_as_uint(dsq), 0u);
  }

  const short8* __restrict__ w2x_f = (const short8*)wbuf;
  short8 a2w[4];
  #pragma unroll
  for (int ks = 0; ks < 4; ++ks) a2w[ks] = w2x_f[(wv*4 + ks)*64 + lane];

  float w1xd[2][4], w1pd[2][4], wp2[2][4], b2xr[4];
  #pragma unroll
  for (int ti = 0; ti < 2; ++ti)
    #pragma unroll
    for (int r = 0; r < 4; ++r) {
      int h = (wv + 4*ti)*16 + quad*4 + r;
      w1xd[ti][r] = W1x[16384 + h];     // dist^2 row (row 128 of [129][128])
      w1pd[ti][r] = W1p[16384 + h];
      wp2[ti][r]  = W2p[h];
    }
  #pragma unroll
  for (int r = 0; r < 4; ++r) b2xr[r] = b2x[wv*16 + quad*4 + r];
  const float b2ps = b2p[0];
  __syncthreads();

  #pragma unroll
  for (int et = 0; et < 4; ++et) {
    uint4 ed = edata[et*16 + lc];
    const float dsqv = __uint_as_float(ed.z);
    float ps = 0.f;
    #pragma unroll
    for (int ti = 0; ti < 2; ++ti) {
      const int ht = wv + 4*ti;
      const int hb = ht*32 + quad*8;
      uint4 va = *(const uint4*)((const unsigned short*)Ar + (size_t)ed.x*256 + hb);
      uint4 vc = *(const uint4*)((const unsigned short*)Ac + (size_t)ed.y*256 + hb);
      float sx[4];
      #pragma unroll
      for (int j = 0; j < 4; ++j) {
        unsigned a = (&va.x)[j], bb = (&vc.x)[j];
        float hx = __uint_as_float(a << 16) + __uint_as_float(bb << 16)
                 + dsqv * w1xd[ti][j];
        float hp = __uint_as_float(a & 0xffff0000u) + __uint_as_float(bb & 0xffff0000u)
                 + dsqv * w1pd[ti][j];
        sx[j] = silu(hx);
        ps += silu(hp) * wp2[ti][j];
      }
      *(uint2*)&H_lds[et*16 + lc][ht*16 + quad*4] =
          make_uint2(pk2bf(sx[0], sx[1]), pk2bf(sx[2], sx[3]));
    }
    ps += __shfl_xor(ps, 16, 64);
    ps += __shfl_xor(ps, 32, 64);
    if (lane < 16) wsum[wv][et*16 + lane] = ps;
  }
  __syncthreads();

  #pragma unroll 2
  for (int et = 0; et < 4; ++et) {
    floatx4 acc = {0,0,0,0};
    #pragma unroll
    for (int ks = 0; ks < 4; ++ks) {
      short8 b = *(const short8*)&H_lds[et*16 + lc][ks*32 + quad*8];
      acc = __builtin_amdgcn_mfma_f32_16x16x32_bf16(a2w[ks], b, acc, 0, 0, 0);
    }
    int edge = et*16 + lc;
    int myc = col_sh[edge];
    float v0 = acc[0] + b2xr[0], v1 = acc[1] + b2xr[1];
    float v2 = acc[2] + b2xr[2], v3 = acc[3] + b2xr[3];
    #pragma unroll
    for (int s = 1; s < 16; s <<= 1) {
      int   nc = __shfl_down(myc, s, 64);
      float n0 = __shfl_down(v0,  s, 64);
      float n1 = __shfl_down(v1,  s, 64);
      float n2 = __shfl_down(v2,  s, 64);
      float n3 = __shfl_down(v3,  s, 64);
      if ((lc + s < 16) && (nc == myc)) { v0 += n0; v1 += n1; v2 += n2; v3 += n3; }
    }
    bool head = (myc >= 0) && (lc == 0 || col_sh[edge-1] != myc);
    if (head) {
      float* dst = out_x + (size_t)myc*64 + wv*16 + quad*4;
      atomicAdd(dst + 0, v0);
      atomicAdd(dst + 1, v1);
      atomicAdd(dst + 2, v2);
      atomicAdd(dst + 3, v3);
    }
  }

  if (t < 64) {
    int c = col_sh[t];
    float w = wsum[0][t] + wsum[1][t] + wsum[2][t] + wsum[3][t] + b2ps;
    float p0 = w * rel_lds[t][0], p1 = w * rel_lds[t][1], p2 = w * rel_lds[t][2];
    #pragma unroll
    for (int s = 1; s < 64; s <<= 1) {
      int   nc = __shfl_down(c,  s, 64);
      float n0 = __shfl_down(p0, s, 64);
      float n1 = __shfl_down(p1, s, 64);
      float n2 = __shfl_down(p2, s, 64);
      if ((t + s < 64) && (nc == c)) { p0 += n0; p1 += n1; p2 += n2; }
    }
    bool head = (c >= 0) && (t == 0 || col_sh[t-1] != c);
    if (head) {
      atomicAdd(&out_pos[(size_t)c*3 + 0], p0);
      atomicAdd(&out_pos[(size_t)c*3 + 1], p1);
      atomicAdd(&out_pos[(size_t)c*3 + 2], p2);
    }
  }
}

extern "C" void kernel_launch(void* const* d_in, const int* in_sizes, int n_in,
                              void* d_out, int out_size, void* d_ws, size_t ws_size,
                              hipStream_t stream) {
  const float* x   = (const float*)d_in[0];
  const float* pos = (const float*)d_in[1];
  const int*   ei  = (const int*)d_in[2];
  const float* W1x = (const float*)d_in[3];
  const float* b1x = (const float*)d_in[4];
  const float* W2x = (const float*)d_in[5];
  const float* b2x = (const float*)d_in[6];
  const float* W1p = (const float*)d_in[7];
  const float* b1p = (const float*)d_in[8];
  const float* W2p = (const float*)d_in[9];
  const float* b2p = (const float*)d_in[10];

  const int E = in_sizes[2] / 2;        // 800000
  const int N = in_sizes[0] / 64;       // 50000
  const int* rowp = ei;
  const int* colp = ei + E;
  float* out_x   = (float*)d_out;
  float* out_pos = out_x + (size_t)N * 64;
  const int NB = (N + 1023) / 1024;     // 49

  // ws layout: [Ar][Ac][wbuf(W2 frags)][hist][bsum][sedge]
  char* ws = (char*)d_ws;
  const size_t tab_one = (size_t)N * 512;
  unsigned int*   Ar   = (unsigned int*)ws;
  unsigned int*   Ac   = (unsigned int*)(ws + tab_one);
  unsigned short* wbuf = (unsigned short*)(ws + 2*tab_one);
  int*  hist  = (int*)(ws + 2*tab_one + 16384);
  int*  bsum  = (int*)(ws + 2*tab_one + 16384 + 200192);
  int2* sedge = (int2*)(ws + 2*tab_one + 16384 + 200192 + 512);

  hipMemsetAsync(hist, 0, (size_t)N * sizeof(int), stream);

  // mega-setup: nodeA | zero d_out | histogram | repack W2x
  const int nb_node = (N + 63) / 64;                 // 782
  const int nb_zero = (out_size + 4095) / 4096;      // 818
  const int nb_hist = ((E >> 2) + 255) / 256;        // 782
  const int nb_rep  = 32;
  const int b1 = nb_node, b2 = b1 + nb_zero, b3 = b2 + nb_hist;
  k_mega<<<b3 + nb_rep, 256, 0, stream>>>(
      (float*)d_out, out_size, colp, E, hist, x, N,
      W1x, W1p, W2x, b1x, b1p, wbuf, Ar, Ac, b1, b2, b3);

  k_scan_a<<<NB, 256, 0, stream>>>(hist, N, bsum);
  k_scatter<<<((E >> 2) + 255) / 256, 256, 0, stream>>>(
      rowp, colp, E, hist, bsum, NB, sedge);

  mp_main<<<(E + 63) / 64, 256, 0, stream>>>(
      pos, sedge, E, Ar, Ac, W1x, W1p, b2x, W2p, b2p, wbuf, out_x, out_pos);
}